// Round 6
// baseline (1885.528 us; speedup 1.0000x reference)
//
#include <hip/hip_runtime.h>
#include <hip/hip_bf16.h>
#include <math.h>

#define B_ 32
#define N_ 256
#define DIM_ 384
#define H_ 6
#define DH_ 64
#define INNER_ 384
#define MLP_ 1536
#define DEPTH_ 12
#define T_ (B_ * N_)   // 8192 tokens

typedef __bf16 bf16x8 __attribute__((ext_vector_type(8)));
typedef __bf16 bf16x4 __attribute__((ext_vector_type(4)));
typedef float f32x4 __attribute__((ext_vector_type(4)));

typedef const __attribute__((address_space(1))) void* gas_ptr;
typedef __attribute__((address_space(3))) void* las_ptr;

// wbuf layout (bf16, per layer, transposed [n][k])
#define WQKV_OFF 0                      // [1152][384]
#define WO_OFF   (1152 * 384)           // [384][384]
#define W1_OFF   (WO_OFF + 384 * 384)   // [1536][384]
#define W2_OFF   (W1_OFF + 1536 * 384)  // [384][1536]
#define WBUF_ELEMS (W2_OFF + 384 * 1536)

// ---------------- weight pre-pack, ALL layers in one dispatch ----------------
__global__ __launch_bounds__(256) void convert_w_all(
    const float* __restrict__ wq0, const float* __restrict__ wkv0,
    const float* __restrict__ wo0, const float* __restrict__ w10,
    const float* __restrict__ w20, __bf16* __restrict__ wbuf0)
{
    __shared__ float til[64][65];
    int t = blockIdx.x;
    int l = t / 432; t -= l * 432;
    const float* wq  = wq0  + (size_t)l * DIM_ * INNER_;
    const float* wkv = wkv0 + (size_t)l * DIM_ * 2 * INNER_;
    const float* wo  = wo0  + (size_t)l * INNER_ * DIM_;
    const float* w1  = w10  + (size_t)l * DIM_ * MLP_;
    const float* w2  = w20  + (size_t)l * MLP_ * DIM_;
    __bf16* wbuf = wbuf0 + (size_t)l * WBUF_ELEMS;

    int lane = threadIdx.x & 63, seg = threadIdx.x >> 6;
    const float* src; __bf16* dst;
    int Ns, sc, dK, dR, k0;
    if (t < 108) {                      // wqkv_t [1152][384]
        int nt = t / 6, kt = t % 6;
        int n0 = nt * 64; k0 = kt * 64;
        dst = wbuf + WQKV_OFF; dK = 384; dR = n0;
        if (n0 < 384) { src = wq;  Ns = 384; sc = n0; }
        else          { src = wkv; Ns = 768; sc = n0 - 384; }
    } else if (t < 144) {               // wo_t [384][384]
        int u = t - 108; int nt = u / 6, kt = u % 6;
        src = wo; Ns = 384; sc = nt * 64;
        dst = wbuf + WO_OFF; dK = 384; dR = nt * 64; k0 = kt * 64;
    } else if (t < 288) {               // w1_t [1536][384]
        int u = t - 144; int nt = u / 6, kt = u % 6;
        src = w1; Ns = 1536; sc = nt * 64;
        dst = wbuf + W1_OFF; dK = 384; dR = nt * 64; k0 = kt * 64;
    } else {                            // w2_t [384][1536]
        int u = t - 288; int nt = u / 24, kt = u % 24;
        src = w2; Ns = 384; sc = nt * 64;
        dst = wbuf + W2_OFF; dK = 1536; dR = nt * 64; k0 = kt * 64;
    }
    #pragma unroll
    for (int r = 0; r < 16; ++r) {
        int i = seg * 16 + r;
        til[i][lane] = src[(size_t)(k0 + i) * Ns + sc + lane];
    }
    __syncthreads();
    #pragma unroll
    for (int r = 0; r < 16; ++r) {
        int i = seg * 16 + r;
        dst[(size_t)(dR + i) * dK + k0 + lane] = (__bf16)til[lane][i];
    }
}

// ---------------- row stats (sum, sumsq) for layer-0 LN1 ----------
__global__ __launch_bounds__(256) void row_stats(
    const float* __restrict__ x, float* __restrict__ st)
{
    size_t row = blockIdx.x * 4 + (threadIdx.x >> 6);
    int lane = threadIdx.x & 63;
    const float* xr = x + row * DIM_;
    float s = 0.f, q2 = 0.f;
    #pragma unroll
    for (int k = 0; k < 6; ++k) { float v = xr[lane + 64 * k]; s += v; q2 += v * v; }
    #pragma unroll
    for (int o = 32; o > 0; o >>= 1) { s += __shfl_xor(s, o); q2 += __shfl_xor(q2, o); }
    if (lane == 0) { st[row * 2] = s; st[row * 2 + 1] = q2; }
}

// ---------------- MFMA GEMM, triple-buffered counted-vmcnt pipeline ----------------
// LNA=false: A + B both via global_load_lds DMA (validated R4/R5 structure).
// LNA=true : A = LayerNorm(xf) fused — reg-stage f32 xf rows, normalize with
//   precomputed row stats (sum,sumsq) + gamma/beta (LDS), cvt bf16, ds_write into
//   the pipeline's A buffers. Bundle order per tile t: [4 A-loads, 2 B-DMA].
//   Compiler auto-drains through A(i+1) at the transform (writeA); manual
//   pre-barrier wait vmcnt(6) leaves A/B(i+1) in flight; never drains B mid-loop.
// MODE2 epilogue: residual write + row-stats accumulation (shfl reduce + atomics)
// for the NEXT LayerNorm. statsZero: zeroed at kernel start by bn==0 blocks
// (stream order guarantees no concurrent accumulator).
template<int MODE, int K, int BM, int BN, int BK, int NT, bool LNA>
__global__ __launch_bounds__(256) void gemmt(
    const __bf16* __restrict__ A, const __bf16* __restrict__ Bt,
    const float* __restrict__ bias, const float* __restrict__ ls,
    float* __restrict__ xf, __bf16* __restrict__ out,
    __bf16* __restrict__ oq, __bf16* __restrict__ ok, __bf16* __restrict__ ov,
    int Nn,
    const float* __restrict__ xin, const float* __restrict__ stats,
    const float* __restrict__ lng, const float* __restrict__ lnb,
    float* __restrict__ statsOut, float* __restrict__ statsZero)
{
    constexpr int WM = BM / 32, WN = BN / 32;
    constexpr int KS = BK / 32;
    constexpr int MT = T_ / BM;
    constexpr int nIter = K / BK;
    constexpr bool SWZ = (BK == 64);
    constexpr int RPI = 512 / BK;                 // rows per DMA instr
    constexpr int CL  = BK / 8;                   // 16B col slots per row
    static_assert(!LNA || (BM == 128 && BK == 32 && K == 384), "LNA mapping");
    static_assert(nIter >= 3, "pipeline needs >=3 K-steps");

    __shared__ __align__(16) __bf16 sA[3][BM * BK];
    __shared__ __align__(16) __bf16 sB[3][BN * BK];
    __shared__ float sLN[LNA ? 768 : 4];

    int id = blockIdx.x;
    constexpr int nxg = (MT * NT) / 8;
    int wg = (id & 7) * nxg + (id >> 3);          // bijective XCD-chunked swizzle
    int bm = (wg / NT) * BM;                      // bm SLOW within XCD chunk
    int bn = (wg % NT) * BN;                      // bn fast -> A-panel reuse in L2
    int tid = threadIdx.x;
    int lane = tid & 63, wid = tid >> 6;
    int wm = (wid & 1) * (BM / 2), wn = (wid >> 1) * (BN / 2);
    int fm = lane & 15, fq = lane >> 4;

    if (statsZero != nullptr && (wg % NT) == 0 && tid < 2 * BM)
        statsZero[(size_t)bm * 2 + tid] = 0.f;

    f32x4 acc[WM][WN] = {};

    int lr = lane / CL, lc = lane % CL;
    int lcs = SWZ ? (lc ^ lr) : lc;               // pre-swizzled source col slot
    const __bf16* bBase = Bt + (size_t)(bn + wid * RPI + lr) * K + lcs * 8;

    auto stageB = [&](int buf, int kk) {
        #pragma unroll
        for (int qI = 0; qI < BN / (4 * RPI); ++qI)
            __builtin_amdgcn_global_load_lds(
                (gas_ptr)(bBase + (size_t)(qI * 4 * RPI) * K + kk),
                (las_ptr)&sB[buf][qI * 2048 + wid * 512], 16, 0, 0);
    };

    auto compute = [&](int cur) {
        bf16x8 af[KS][WM], bfr[KS][WN];
        #pragma unroll
        for (int ks = 0; ks < KS; ++ks) {
            #pragma unroll
            for (int ii = 0; ii < WM; ++ii) {
                int row = wm + ii * 16 + fm;
                int c = SWZ ? (((ks * 4 + fq) ^ (row & 7)) * 8) : (ks * 32 + fq * 8);
                af[ks][ii] = *(const bf16x8*)&sA[cur][row * BK + c];
            }
            #pragma unroll
            for (int jj = 0; jj < WN; ++jj) {
                int row = wn + jj * 16 + fm;
                int c = SWZ ? (((ks * 4 + fq) ^ (row & 7)) * 8) : (ks * 32 + fq * 8);
                bfr[ks][jj] = *(const bf16x8*)&sB[cur][row * BK + c];
            }
        }
        #pragma unroll
        for (int ks = 0; ks < KS; ++ks)
            #pragma unroll
            for (int ii = 0; ii < WM; ++ii)
                #pragma unroll
                for (int jj = 0; jj < WN; ++jj)
                    acc[ii][jj] = __builtin_amdgcn_mfma_f32_16x16x32_bf16(
                        af[ks][ii], bfr[ks][jj], acc[ii][jj], 0, 0, 0);
    };

    if constexpr (LNA) {
        // ---- LN-fused A path ----
        int r0 = wid * 32 + lr, r1 = r0 + 16;     // two rows per thread
        for (int t2 = tid; t2 < 384; t2 += 256) { sLN[t2] = lng[t2]; sLN[384 + t2] = lnb[t2]; }
        __syncthreads();                           // sLN visible; vmcnt/lgkm == 0 baseline

        float2 st0 = *(const float2*)&stats[(size_t)(bm + r0) * 2];
        float2 st1 = *(const float2*)&stats[(size_t)(bm + r1) * 2];
        float mu0 = st0.x * (1.f / 384.f), mu1 = st1.x * (1.f / 384.f);
        float rs0 = rsqrtf(st0.y * (1.f / 384.f) - mu0 * mu0 + 1e-5f);
        float rs1 = rsqrtf(st1.y * (1.f / 384.f) - mu1 * mu1 + 1e-5f);
        __builtin_amdgcn_sched_barrier(0);         // pin stats loads+math above bundles

        f32x4 ar[2][2][2];                         // [set][row][half] — static idx only
        const float* xr0 = xin + (size_t)(bm + r0) * 384 + lc * 8;
        const float* xr1 = xin + (size_t)(bm + r1) * 384 + lc * 8;
        auto loadA = [&](int set, int t) {
            ar[set][0][0] = *(const f32x4*)(xr0 + t * 32);
            ar[set][0][1] = *(const f32x4*)(xr0 + t * 32 + 4);
            ar[set][1][0] = *(const f32x4*)(xr1 + t * 32);
            ar[set][1][1] = *(const f32x4*)(xr1 + t * 32 + 4);
        };
        auto writeA = [&](int set, int buf, int t) {
            f32x4 gv0 = *(const f32x4*)&sLN[t * 32 + lc * 8];
            f32x4 gv1 = *(const f32x4*)&sLN[t * 32 + lc * 8 + 4];
            f32x4 bv0 = *(const f32x4*)&sLN[384 + t * 32 + lc * 8];
            f32x4 bv1 = *(const f32x4*)&sLN[384 + t * 32 + lc * 8 + 4];
            bf16x8 w0, w1;
            #pragma unroll
            for (int k2 = 0; k2 < 4; ++k2) {
                w0[k2]     = (__bf16)((ar[set][0][0][k2] - mu0) * rs0 * gv0[k2] + bv0[k2]);
                w0[k2 + 4] = (__bf16)((ar[set][0][1][k2] - mu0) * rs0 * gv1[k2] + bv1[k2]);
                w1[k2]     = (__bf16)((ar[set][1][0][k2] - mu1) * rs1 * gv0[k2] + bv0[k2]);
                w1[k2 + 4] = (__bf16)((ar[set][1][1][k2] - mu1) * rs1 * gv1[k2] + bv1[k2]);
            }
            *(bf16x8*)&sA[buf][r0 * 32 + lc * 8] = w0;
            *(bf16x8*)&sA[buf][r1 * 32 + lc * 8] = w1;
        };

        loadA(0, 0); stageB(0, 0);                 // bundle(0): [A x4, B x2]
        loadA(1, 1); stageB(1, BK);                // bundle(1)
        writeA(0, 0, 0);                           // compiler drains through A(0) -> leaves 8

        #pragma unroll
        for (int i = 0; i < nIter; ++i) {
            int cur = i % 3;
            // need B(i) landed; leave A(i+1),B(i+1) in flight
            if (i + 1 < nIter) asm volatile("s_waitcnt vmcnt(6)" ::: "memory");
            else               asm volatile("s_waitcnt vmcnt(0)" ::: "memory");
            asm volatile("s_waitcnt lgkmcnt(0)" ::: "memory");   // drain our ds_writes
            __builtin_amdgcn_sched_barrier(0);
            __builtin_amdgcn_s_barrier();
            __builtin_amdgcn_sched_barrier(0);
            if (i + 2 < nIter) { loadA(i % 2, i + 2); stageB((i + 2) % 3, (i + 2) * BK); }
            if (i + 1 < nIter) writeA((i + 1) % 2, (i + 1) % 3, i + 1);
            compute(cur);
        }
    } else {
        // ---- DMA A+B path (validated R4/R5 structure) ----
        const __bf16* aBase = A + (size_t)(bm + wid * RPI + lr) * K + lcs * 8;
        auto stageA = [&](int buf, int kk) {
            #pragma unroll
            for (int qI = 0; qI < BM / (4 * RPI); ++qI)
                __builtin_amdgcn_global_load_lds(
                    (gas_ptr)(aBase + (size_t)(qI * 4 * RPI) * K + kk),
                    (las_ptr)&sA[buf][qI * 2048 + wid * 512], 16, 0, 0);
        };
        stageA(0, 0); stageB(0, 0);
        stageA(1, BK); stageB(1, BK);              // 8 loads in flight

        #pragma unroll
        for (int i = 0; i < nIter; ++i) {
            int cur = i % 3;
            if (i + 1 < nIter)
                asm volatile("s_waitcnt vmcnt(4)" ::: "memory");   // tile i resident
            else
                asm volatile("s_waitcnt vmcnt(0)" ::: "memory");
            __builtin_amdgcn_s_barrier();
            __builtin_amdgcn_sched_barrier(0);
            if (i + 2 < nIter) { stageA((i + 2) % 3, (i + 2) * BK); stageB((i + 2) % 3, (i + 2) * BK); }
            compute(cur);
        }
    }

    // epilogue: C/D layout col=lane&15, row=(lane>>4)*4+reg
    float sS[WM][4], sQ[WM][4];
    if constexpr (MODE == 2) {
        #pragma unroll
        for (int ii = 0; ii < WM; ++ii)
            #pragma unroll
            for (int r = 0; r < 4; ++r) { sS[ii][r] = 0.f; sQ[ii][r] = 0.f; }
    }
    #pragma unroll
    for (int jj = 0; jj < WN; ++jj) {
        int col = bn + wn + jj * 16 + fm;
        float bv = (MODE != 0) ? bias[col] : 0.0f;
        float lv = (MODE == 2) ? ls[col] : 0.0f;
        #pragma unroll
        for (int ii = 0; ii < WM; ++ii) {
            #pragma unroll
            for (int r = 0; r < 4; ++r) {
                int row = bm + wm + ii * 16 + fq * 4 + r;
                float v = acc[ii][jj][r];
                if (MODE == 0) {
                    if (col < 384)      oq[(size_t)row * 384 + col] = (__bf16)v;
                    else if (col < 768) ok[(size_t)row * 384 + col - 384] = (__bf16)v;
                    else {
                        int bb = row >> 8, tj = row & 255;
                        ov[((size_t)bb * 384 + (col - 768)) * 256 + tj] = (__bf16)v;
                    }
                } else if (MODE == 1) {
                    v += bv;
                    v = 0.5f * v * (1.0f + erff(v * 0.70710678118f));
                    out[(size_t)row * Nn + col] = (__bf16)v;
                } else {
                    size_t idx = (size_t)row * Nn + col;
                    float nv = (v + bv) * lv + xf[idx];
                    xf[idx] = nv;
                    sS[ii][r] += nv; sQ[ii][r] += nv * nv;
                }
            }
        }
    }
    if constexpr (MODE == 2) {
        if (statsOut != nullptr) {
            #pragma unroll
            for (int ii = 0; ii < WM; ++ii) {
                #pragma unroll
                for (int r = 0; r < 4; ++r) {
                    float a = sS[ii][r], b = sQ[ii][r];
                    #pragma unroll
                    for (int o = 8; o > 0; o >>= 1) { a += __shfl_xor(a, o); b += __shfl_xor(b, o); }
                    if (fm == 0) {
                        int row = bm + wm + ii * 16 + fq * 4 + r;
                        atomicAdd(&statsOut[(size_t)row * 2], a);
                        atomicAdd(&statsOut[(size_t)row * 2 + 1], b);
                    }
                }
            }
        }
    }
}

// ---------------- fused MFMA talking-heads attention (v3) ----------------
#define PAD_S 264

__global__ __launch_bounds__(384) void attn_mfma(
    const __bf16* __restrict__ q, const __bf16* __restrict__ kb,
    const __bf16* __restrict__ vT, const float* __restrict__ scale,
    const float* __restrict__ mp, const float* __restrict__ mq,
    __bf16* __restrict__ o)
{
    __shared__ __bf16 sbuf[96][PAD_S];

    int id = blockIdx.x;
    int b = (id & 7) + ((id >> 3) & 3) * 8;
    int i0 = (id >> 5) * 16;
    int tid = threadIdx.x;
    int lane = tid & 63, wid = tid >> 6;
    int fm = lane & 15, fq = lane >> 4;

    // ---- Phase 1 — QK^T: wave h computes raw S_h[16][256] ----
    int h = wid;
    bf16x8 qf[2];
    #pragma unroll
    for (int ks = 0; ks < 2; ++ks)
        qf[ks] = *(const bf16x8*)&q[(size_t)(b * 256 + i0 + fm) * 384 + h * 64 + ks * 32 + fq * 8];
    #pragma unroll 4
    for (int jt = 0; jt < 16; ++jt) {
        f32x4 a = {};
        #pragma unroll
        for (int ks = 0; ks < 2; ++ks) {
            bf16x8 bfr = *(const bf16x8*)&kb[(size_t)(b * 256 + jt * 16 + fm) * 384 + h * 64 + ks * 32 + fq * 8];
            a = __builtin_amdgcn_mfma_f32_16x16x32_bf16(qf[ks], bfr, a, 0, 0, 0);
        }
        #pragma unroll
        for (int r = 0; r < 4; ++r)
            sbuf[h * 16 + fq * 4 + r][jt * 16 + fm] = (__bf16)a[r];
    }

    float mps[36], mqs[36];
    #pragma unroll
    for (int t = 0; t < 36; ++t) { mps[t] = mp[t] * scale[t / 6]; mqs[t] = mq[t]; }

    __syncthreads();

    // ---- Phase 2 — fused premix + mask + softmax + postmix, wave per row ----
    for (int i = wid; i < 16; i += 6) {
        float sv[6][4];
        #pragma unroll
        for (int h2 = 0; h2 < 6; ++h2) {
            bf16x4 v4 = *(const bf16x4*)&sbuf[h2 * 16 + i][lane * 4];
            #pragma unroll
            for (int c = 0; c < 4; ++c) sv[h2][c] = (float)v4[c];
        }
        int drow = i0 + i;
        float pv[6][4];
        #pragma unroll
        for (int g2 = 0; g2 < 6; ++g2) {
            float t0[4];
            #pragma unroll
            for (int c = 0; c < 4; ++c) {
                float r2 = 0.f;
                #pragma unroll
                for (int h2 = 0; h2 < 6; ++h2) r2 += sv[h2][c] * mps[h2 * 6 + g2];
                t0[c] = (lane * 4 + c == drow) ? -1e30f : r2;
            }
            float m = fmaxf(fmaxf(t0[0], t0[1]), fmaxf(t0[2], t0[3]));
            #pragma unroll
            for (int off = 32; off > 0; off >>= 1) m = fmaxf(m, __shfl_xor(m, off));
            float e0 = __expf(t0[0] - m), e1 = __expf(t0[1] - m);
            float e2 = __expf(t0[2] - m), e3 = __expf(t0[3] - m);
            float s = e0 + e1 + e2 + e3;
            #pragma unroll
            for (int off = 32; off > 0; off >>= 1) s += __shfl_xor(s, off);
            float inv = 1.0f / s;
            pv[g2][0] = e0 * inv; pv[g2][1] = e1 * inv;
            pv[g2][2] = e2 * inv; pv[g2][3] = e3 * inv;
        }
        #pragma unroll
        for (int g2 = 0; g2 < 6; ++g2) {
            bf16x4 w4;
            #pragma unroll
            for (int c = 0; c < 4; ++c) {
                float r2 = 0.f;
                #pragma unroll
                for (int h2 = 0; h2 < 6; ++h2) r2 += pv[h2][c] * mqs[h2 * 6 + g2];
                w4[c] = (__bf16)r2;
            }
            *(bf16x4*)&sbuf[g2 * 16 + i][lane * 4] = w4;
        }
    }
    __syncthreads();

    // ---- Phase 3 — P @ V ----
    int gg = wid;
    f32x4 acco[4] = {};
    #pragma unroll
    for (int jc = 0; jc < 4; ++jc) {
        #pragma unroll
        for (int ks = 0; ks < 2; ++ks) {
            bf16x8 af = *(const bf16x8*)&sbuf[gg * 16 + fm][jc * 64 + ks * 32 + fq * 8];
            #pragma unroll
            for (int nt = 0; nt < 4; ++nt) {
                bf16x8 bfr = *(const bf16x8*)&vT[(size_t)(b * 384 + gg * 64 + nt * 16 + fm) * 256 + jc * 64 + ks * 32 + fq * 8];
                acco[nt] = __builtin_amdgcn_mfma_f32_16x16x32_bf16(af, bfr, acco[nt], 0, 0, 0);
            }
        }
    }
    #pragma unroll
    for (int nt = 0; nt < 4; ++nt)
        #pragma unroll
        for (int r = 0; r < 4; ++r)
            o[(size_t)(b * 256 + i0 + fq * 4 + r) * 384 + gg * 64 + nt * 16 + fm] = (__bf16)acco[nt][r];
}

extern "C" void kernel_launch(void* const* d_in, const int* in_sizes, int n_in,
                              void* d_out, int out_size, void* d_ws, size_t ws_size,
                              hipStream_t stream) {
    const float* x      = (const float*)d_in[0];
    const float* ln1_g  = (const float*)d_in[1];
    const float* ln1_b  = (const float*)d_in[2];
    const float* wq     = (const float*)d_in[3];
    const float* wkv    = (const float*)d_in[4];
    const float* scale  = (const float*)d_in[5];
    const float* mixp   = (const float*)d_in[6];
    const float* mixq   = (const float*)d_in[7];
    const float* wo     = (const float*)d_in[8];
    const float* bo     = (const float*)d_in[9];
    const float* ls1    = (const float*)d_in[10];
    const float* ln2_g  = (const float*)d_in[11];
    const float* ln2_b  = (const float*)d_in[12];
    const float* w1     = (const float*)d_in[13];
    const float* b1     = (const float*)d_in[14];
    const float* w2     = (const float*)d_in[15];
    const float* b2     = (const float*)d_in[16];
    const float* ls2    = (const float*)d_in[17];

    char* ws = (char*)d_ws;
    float*  xf = (float*)ws;                      ws += (size_t)T_ * DIM_ * 4;
    float*  statsLn1 = (float*)ws;                // [T][2] — consumed by QKV (ln1)
    float*  statsLn2 = statsLn1 + 2 * T_;         // [T][2] — consumed by MLP1 (ln2)
    ws += (size_t)T_ * DIM_ * 2;                  // (reuses old y slot; 64KB+64KB used)
    __bf16* q  = (__bf16*)ws;                     ws += (size_t)T_ * DIM_ * 2;
    __bf16* kb = (__bf16*)ws;                     ws += (size_t)T_ * DIM_ * 2;
    __bf16* vT = (__bf16*)ws;                     ws += (size_t)T_ * DIM_ * 2;
    __bf16* o  = (__bf16*)ws;                     ws += (size_t)T_ * DIM_ * 2;
    __bf16* wbuf = (__bf16*)ws;                   ws += (size_t)WBUF_ELEMS * DEPTH_ * 2;
    __bf16* h  = q;   // MLP hidden [T][1536] overlays q+kb+vT+o (dead by then)

    size_t nBytes = (size_t)T_ * DIM_ * sizeof(float);
    hipMemcpyAsync(xf, x, nBytes, hipMemcpyDeviceToDevice, stream);

    convert_w_all<<<432 * DEPTH_, 256, 0, stream>>>(wq, wkv, wo, w1, w2, wbuf);
    row_stats<<<T_ / 4, 256, 0, stream>>>(xf, statsLn1);   // seed layer-0 ln1 stats

    for (int l = 0; l < DEPTH_; ++l) {
        __bf16* wl = wbuf + (size_t)l * WBUF_ELEMS;

        // QKV (LN1-fused): consumes statsLn1; zeroes statsLn2 for O-proj
        gemmt<0, 384, 128, 128, 32, 9, true><<<576, 256, 0, stream>>>(
            nullptr, wl + WQKV_OFF, nullptr, nullptr, nullptr, nullptr,
            q, kb, vT, 1152,
            xf, statsLn1, ln1_g + (size_t)l * DIM_, ln1_b + (size_t)l * DIM_,
            nullptr, statsLn2);

        attn_mfma<<<512, 384, 0, stream>>>(
            q, kb, vT, scale + (size_t)l * H_,
            mixp + (size_t)l * H_ * H_, mixq + (size_t)l * H_ * H_, o);

        // O-proj: accumulates statsLn2 (for ln2); zeroes statsLn1 for MLP2
        gemmt<2, 384, 64, 64, 64, 6, false><<<768, 256, 0, stream>>>(
            o, wl + WO_OFF, bo + (size_t)l * DIM_, ls1 + (size_t)l * DIM_,
            xf, nullptr, nullptr, nullptr, nullptr, DIM_,
            nullptr, nullptr, nullptr, nullptr, statsLn2, statsLn1);

        // MLP1 (LN2-fused): consumes statsLn2
        gemmt<1, 384, 128, 128, 32, 12, true><<<768, 256, 0, stream>>>(
            nullptr, wl + W1_OFF, b1 + (size_t)l * MLP_, nullptr,
            nullptr, h, nullptr, nullptr, nullptr, MLP_,
            xf, statsLn2, ln2_g + (size_t)l * DIM_, ln2_b + (size_t)l * DIM_,
            nullptr, nullptr);

        // MLP2: accumulates statsLn1 (for next layer's ln1)
        gemmt<2, 1536, 64, 64, 64, 6, false><<<768, 256, 0, stream>>>(
            h, wl + W2_OFF, b2 + (size_t)l * DIM_, ls2 + (size_t)l * DIM_,
            xf, nullptr, nullptr, nullptr, nullptr, DIM_,
            nullptr, nullptr, nullptr, nullptr, statsLn1, nullptr);
    }

    hipMemcpyAsync(d_out, xf, nBytes, hipMemcpyDeviceToDevice, stream);
}

// Round 8
// 1719.586 us; speedup vs baseline: 1.0965x; 1.0965x over previous
//
#include <hip/hip_runtime.h>
#include <hip/hip_bf16.h>
#include <math.h>

#define B_ 32
#define N_ 256
#define DIM_ 384
#define H_ 6
#define DH_ 64
#define INNER_ 384
#define MLP_ 1536
#define DEPTH_ 12
#define T_ (B_ * N_)   // 8192 tokens

typedef __bf16 bf16x8 __attribute__((ext_vector_type(8)));
typedef __bf16 bf16x4 __attribute__((ext_vector_type(4)));
typedef float f32x4 __attribute__((ext_vector_type(4)));

typedef const __attribute__((address_space(1))) void* gas_ptr;
typedef __attribute__((address_space(3))) void* las_ptr;

// wbuf layout (bf16, per layer, transposed [n][k])
#define WQKV_OFF 0                      // [1152][384]
#define WO_OFF   (1152 * 384)           // [384][384]
#define W1_OFF   (WO_OFF + 384 * 384)   // [1536][384]
#define W2_OFF   (W1_OFF + 1536 * 384)  // [384][1536]
#define WBUF_ELEMS (W2_OFF + 384 * 1536)

// ---------------- weight pre-pack, ALL layers in one dispatch ----------------
__global__ __launch_bounds__(256) void convert_w_all(
    const float* __restrict__ wq0, const float* __restrict__ wkv0,
    const float* __restrict__ wo0, const float* __restrict__ w10,
    const float* __restrict__ w20, __bf16* __restrict__ wbuf0)
{
    __shared__ float til[64][65];
    int t = blockIdx.x;
    int l = t / 432; t -= l * 432;
    const float* wq  = wq0  + (size_t)l * DIM_ * INNER_;
    const float* wkv = wkv0 + (size_t)l * DIM_ * 2 * INNER_;
    const float* wo  = wo0  + (size_t)l * INNER_ * DIM_;
    const float* w1  = w10  + (size_t)l * DIM_ * MLP_;
    const float* w2  = w20  + (size_t)l * MLP_ * DIM_;
    __bf16* wbuf = wbuf0 + (size_t)l * WBUF_ELEMS;

    int lane = threadIdx.x & 63, seg = threadIdx.x >> 6;
    const float* src; __bf16* dst;
    int Ns, sc, dK, dR, k0;
    if (t < 108) {                      // wqkv_t [1152][384]
        int nt = t / 6, kt = t % 6;
        int n0 = nt * 64; k0 = kt * 64;
        dst = wbuf + WQKV_OFF; dK = 384; dR = n0;
        if (n0 < 384) { src = wq;  Ns = 384; sc = n0; }
        else          { src = wkv; Ns = 768; sc = n0 - 384; }
    } else if (t < 144) {               // wo_t [384][384]
        int u = t - 108; int nt = u / 6, kt = u % 6;
        src = wo; Ns = 384; sc = nt * 64;
        dst = wbuf + WO_OFF; dK = 384; dR = nt * 64; k0 = kt * 64;
    } else if (t < 288) {               // w1_t [1536][384]
        int u = t - 144; int nt = u / 6, kt = u % 6;
        src = w1; Ns = 1536; sc = nt * 64;
        dst = wbuf + W1_OFF; dK = 384; dR = nt * 64; k0 = kt * 64;
    } else {                            // w2_t [384][1536]
        int u = t - 288; int nt = u / 24, kt = u % 24;
        src = w2; Ns = 384; sc = nt * 64;
        dst = wbuf + W2_OFF; dK = 1536; dR = nt * 64; k0 = kt * 64;
    }
    #pragma unroll
    for (int r = 0; r < 16; ++r) {
        int i = seg * 16 + r;
        til[i][lane] = src[(size_t)(k0 + i) * Ns + sc + lane];
    }
    __syncthreads();
    #pragma unroll
    for (int r = 0; r < 16; ++r) {
        int i = seg * 16 + r;
        dst[(size_t)(dR + i) * dK + k0 + lane] = (__bf16)til[lane][i];
    }
}

// ---------------- layernorm: wave per token, 4 tokens per block ----------
__global__ __launch_bounds__(256) void ln1w(
    const float* __restrict__ x, const float* __restrict__ g,
    const float* __restrict__ b, __bf16* __restrict__ y)
{
    size_t row = blockIdx.x * 4 + (threadIdx.x >> 6);
    int lane = threadIdx.x & 63;
    const float* xr = x + row * DIM_;
    float v[6];
    #pragma unroll
    for (int s = 0; s < 6; ++s) v[s] = xr[lane + 64 * s];
    float sum = 0.f;
    #pragma unroll
    for (int s = 0; s < 6; ++s) sum += v[s];
    #pragma unroll
    for (int o = 32; o > 0; o >>= 1) sum += __shfl_xor(sum, o);
    float mu = sum * (1.0f / DIM_);
    float var = 0.f;
    #pragma unroll
    for (int s = 0; s < 6; ++s) { float d = v[s] - mu; var += d * d; }
    #pragma unroll
    for (int o = 32; o > 0; o >>= 1) var += __shfl_xor(var, o);
    float rs = rsqrtf(var * (1.0f / DIM_) + 1e-5f);
    __bf16* yr = y + row * DIM_;
    #pragma unroll
    for (int s = 0; s < 6; ++s) {
        int e = lane + 64 * s;
        yr[e] = (__bf16)((v[s] - mu) * rs * g[e] + b[e]);
    }
}

// ---------------- m97-structure MFMA GEMM + counted-vmcnt pipeline (R4, verified) ----------
template<int MODE, int K, int BM, int BN, int BK, int NT>
__global__ __launch_bounds__(256) void gemmt(
    const __bf16* __restrict__ A, const __bf16* __restrict__ Bt,
    const float* __restrict__ bias, const float* __restrict__ ls,
    float* __restrict__ xf, __bf16* __restrict__ out,
    __bf16* __restrict__ oq, __bf16* __restrict__ ok, __bf16* __restrict__ ov,
    int Nn)
{
    constexpr int WM = BM / 32, WN = BN / 32;
    constexpr int KS = BK / 32;
    constexpr int MT = T_ / BM;
    constexpr int nIter = K / BK;
    constexpr bool SWZ = (BK == 64);
    constexpr int RPI = 512 / BK;                 // rows per stage instr (1 KB each)
    constexpr int CL  = BK / 8;                   // 16B col slots per row
    constexpr int LPT = BM / (4 * RPI) + BN / (4 * RPI);
    static_assert(LPT == 4, "vmcnt literals assume 4 loads per tile per wave");

    __shared__ __align__(16) __bf16 sA[2][BM * BK];
    __shared__ __align__(16) __bf16 sB[2][BN * BK];

    int id = blockIdx.x;
    constexpr int nxg = (MT * NT) / 8;
    int wg = (id & 7) * nxg + (id >> 3);          // bijective XCD-chunked swizzle
    int bm = (wg / NT) * BM;                      // bm SLOW within XCD chunk
    int bn = (wg % NT) * BN;                      // bn fast -> A-panel reuse in L2
    int tid = threadIdx.x;
    int lane = tid & 63, wid = tid >> 6;
    int wm = (wid & 1) * (BM / 2), wn = (wid >> 1) * (BN / 2);
    int fm = lane & 15, fq = lane >> 4;

    f32x4 acc[WM][WN] = {};

    int lr = lane / CL, lc = lane % CL;
    int lcs = SWZ ? (lc ^ lr) : lc;               // pre-swizzled source col slot
    const __bf16* aBase = A + (size_t)(bm + wid * RPI + lr) * K + lcs * 8;
    const __bf16* bBase = Bt + (size_t)(bn + wid * RPI + lr) * K + lcs * 8;

    auto stage = [&](int buf, int kk) {
        #pragma unroll
        for (int qI = 0; qI < BM / (4 * RPI); ++qI)
            __builtin_amdgcn_global_load_lds(
                (gas_ptr)(aBase + (size_t)(qI * 4 * RPI) * K + kk),
                (las_ptr)&sA[buf][qI * 2048 + wid * 512], 16, 0, 0);
        #pragma unroll
        for (int qI = 0; qI < BN / (4 * RPI); ++qI)
            __builtin_amdgcn_global_load_lds(
                (gas_ptr)(bBase + (size_t)(qI * 4 * RPI) * K + kk),
                (las_ptr)&sB[buf][qI * 2048 + wid * 512], 16, 0, 0);
    };

    stage(0, 0);   // 4 loads in flight

    #pragma unroll
    for (int i = 0; i < nIter; ++i) {
        int cur = i & 1;
        if (i + 1 < nIter) {
            stage(cur ^ 1, (i + 1) * BK);                      // +4 loads (next tile)
            asm volatile("s_waitcnt vmcnt(4)" ::: "memory");   // tile i resident
        } else {
            asm volatile("s_waitcnt vmcnt(0)" ::: "memory");
        }
        __builtin_amdgcn_s_barrier();
        __builtin_amdgcn_sched_barrier(0);

        bf16x8 af[KS][WM], bfr[KS][WN];
        #pragma unroll
        for (int ks = 0; ks < KS; ++ks) {
            #pragma unroll
            for (int ii = 0; ii < WM; ++ii) {
                int row = wm + ii * 16 + fm;
                int c = SWZ ? (((ks * 4 + fq) ^ (row & 7)) * 8) : (ks * 32 + fq * 8);
                af[ks][ii] = *(const bf16x8*)&sA[cur][row * BK + c];
            }
            #pragma unroll
            for (int jj = 0; jj < WN; ++jj) {
                int row = wn + jj * 16 + fm;
                int c = SWZ ? (((ks * 4 + fq) ^ (row & 7)) * 8) : (ks * 32 + fq * 8);
                bfr[ks][jj] = *(const bf16x8*)&sB[cur][row * BK + c];
            }
        }
        #pragma unroll
        for (int ks = 0; ks < KS; ++ks)
            #pragma unroll
            for (int ii = 0; ii < WM; ++ii)
                #pragma unroll
                for (int jj = 0; jj < WN; ++jj)
                    acc[ii][jj] = __builtin_amdgcn_mfma_f32_16x16x32_bf16(
                        af[ks][ii], bfr[ks][jj], acc[ii][jj], 0, 0, 0);

        if (i + 1 < nIter) {
            asm volatile("s_waitcnt lgkmcnt(0)" ::: "memory");
            __builtin_amdgcn_sched_barrier(0);
            __builtin_amdgcn_s_barrier();
            __builtin_amdgcn_sched_barrier(0);
        }
    }

    // epilogue: C/D layout col=lane&15, row=(lane>>4)*4+reg
    #pragma unroll
    for (int jj = 0; jj < WN; ++jj) {
        int col = bn + wn + jj * 16 + fm;
        float bv = (MODE != 0) ? bias[col] : 0.0f;
        float lv = (MODE == 2) ? ls[col] : 0.0f;
        #pragma unroll
        for (int ii = 0; ii < WM; ++ii) {
            #pragma unroll
            for (int r = 0; r < 4; ++r) {
                int row = bm + wm + ii * 16 + fq * 4 + r;
                float v = acc[ii][jj][r];
                if (MODE == 0) {
                    if (col < 384)      oq[(size_t)row * 384 + col] = (__bf16)v;
                    else if (col < 768) ok[(size_t)row * 384 + col - 384] = (__bf16)v;
                    else {
                        int bb = row >> 8, tj = row & 255;
                        ov[((size_t)bb * 384 + (col - 768)) * 256 + tj] = (__bf16)v;
                    }
                } else if (MODE == 1) {
                    v += bv;
                    v = 0.5f * v * (1.0f + erff(v * 0.70710678118f));
                    out[(size_t)row * Nn + col] = (__bf16)v;
                } else {
                    size_t idx = (size_t)row * Nn + col;
                    xf[idx] = (v + bv) * lv + xf[idx];
                }
            }
        }
    }
}

// ---------------- fused MFMA talking-heads attention + O-projection (v4) ----------------
// Phases 1-3 as v3 (verified). Phase 4: each block holds full O[16][384] after PV;
// stage into LDS (XOR-swizzled, rule-21 involution), then wave g computes output cols
// g*64..+63 via MFMA with B-frags streamed from L2-resident pre-packed wo_t[n][k];
// epilogue applies bias + LayerScale + residual into xf. Removes the O-proj dispatch
// and the o HBM round-trip.
#define PAD_S 264

__global__ __launch_bounds__(384) void attn_mfma(
    const __bf16* __restrict__ q, const __bf16* __restrict__ kb,
    const __bf16* __restrict__ vT, const float* __restrict__ scale,
    const float* __restrict__ mp, const float* __restrict__ mq,
    const __bf16* __restrict__ wot, const float* __restrict__ bo,
    const float* __restrict__ ls, float* __restrict__ xf)
{
    __shared__ __align__(16) __bf16 sbuf[96][PAD_S];

    int id = blockIdx.x;
    int b = (id & 7) + ((id >> 3) & 3) * 8;
    int i0 = (id >> 5) * 16;
    int tid = threadIdx.x;
    int lane = tid & 63, wid = tid >> 6;
    int fm = lane & 15, fq = lane >> 4;

    // ---- Phase 1 — QK^T: wave h computes raw S_h[16][256] ----
    int h = wid;
    bf16x8 qf[2];
    #pragma unroll
    for (int ks = 0; ks < 2; ++ks)
        qf[ks] = *(const bf16x8*)&q[(size_t)(b * 256 + i0 + fm) * 384 + h * 64 + ks * 32 + fq * 8];
    #pragma unroll 4
    for (int jt = 0; jt < 16; ++jt) {
        f32x4 a = {};
        #pragma unroll
        for (int ks = 0; ks < 2; ++ks) {
            bf16x8 bfr = *(const bf16x8*)&kb[(size_t)(b * 256 + jt * 16 + fm) * 384 + h * 64 + ks * 32 + fq * 8];
            a = __builtin_amdgcn_mfma_f32_16x16x32_bf16(qf[ks], bfr, a, 0, 0, 0);
        }
        #pragma unroll
        for (int r = 0; r < 4; ++r)
            sbuf[h * 16 + fq * 4 + r][jt * 16 + fm] = (__bf16)a[r];
    }

    float mps[36], mqs[36];
    #pragma unroll
    for (int t = 0; t < 36; ++t) { mps[t] = mp[t] * scale[t / 6]; mqs[t] = mq[t]; }

    __syncthreads();

    // ---- Phase 2 — fused premix + mask + softmax + postmix, wave per row ----
    for (int i = wid; i < 16; i += 6) {
        float sv[6][4];
        #pragma unroll
        for (int h2 = 0; h2 < 6; ++h2) {
            bf16x4 v4 = *(const bf16x4*)&sbuf[h2 * 16 + i][lane * 4];
            #pragma unroll
            for (int c = 0; c < 4; ++c) sv[h2][c] = (float)v4[c];
        }
        int drow = i0 + i;
        float pv[6][4];
        #pragma unroll
        for (int g2 = 0; g2 < 6; ++g2) {
            float t0[4];
            #pragma unroll
            for (int c = 0; c < 4; ++c) {
                float r2 = 0.f;
                #pragma unroll
                for (int h2 = 0; h2 < 6; ++h2) r2 += sv[h2][c] * mps[h2 * 6 + g2];
                t0[c] = (lane * 4 + c == drow) ? -1e30f : r2;
            }
            float m = fmaxf(fmaxf(t0[0], t0[1]), fmaxf(t0[2], t0[3]));
            #pragma unroll
            for (int off = 32; off > 0; off >>= 1) m = fmaxf(m, __shfl_xor(m, off));
            float e0 = __expf(t0[0] - m), e1 = __expf(t0[1] - m);
            float e2 = __expf(t0[2] - m), e3 = __expf(t0[3] - m);
            float s = e0 + e1 + e2 + e3;
            #pragma unroll
            for (int off = 32; off > 0; off >>= 1) s += __shfl_xor(s, off);
            float inv = 1.0f / s;
            pv[g2][0] = e0 * inv; pv[g2][1] = e1 * inv;
            pv[g2][2] = e2 * inv; pv[g2][3] = e3 * inv;
        }
        #pragma unroll
        for (int g2 = 0; g2 < 6; ++g2) {
            bf16x4 w4;
            #pragma unroll
            for (int c = 0; c < 4; ++c) {
                float r2 = 0.f;
                #pragma unroll
                for (int h2 = 0; h2 < 6; ++h2) r2 += pv[h2][c] * mqs[h2 * 6 + g2];
                w4[c] = (__bf16)r2;
            }
            *(bf16x4*)&sbuf[g2 * 16 + i][lane * 4] = w4;
        }
    }
    __syncthreads();

    // ---- Phase 3 — P @ V: wave g computes O_g[16 rows][64 cols] ----
    int gg = wid;
    f32x4 acco[4] = {};
    #pragma unroll
    for (int jc = 0; jc < 4; ++jc) {
        #pragma unroll
        for (int ks = 0; ks < 2; ++ks) {
            bf16x8 af = *(const bf16x8*)&sbuf[gg * 16 + fm][jc * 64 + ks * 32 + fq * 8];
            #pragma unroll
            for (int nt = 0; nt < 4; ++nt) {
                bf16x8 bfr = *(const bf16x8*)&vT[(size_t)(b * 384 + gg * 64 + nt * 16 + fm) * 256 + jc * 64 + ks * 32 + fq * 8];
                acco[nt] = __builtin_amdgcn_mfma_f32_16x16x32_bf16(af, bfr, acco[nt], 0, 0, 0);
            }
        }
    }

    // ---- Phase 4 — fused O-projection + LayerScale + residual ----
    __syncthreads();                      // all waves' P reads done; sbuf reusable
    __bf16* oB = &sbuf[0][0];             // O[16][384], XOR-swizzled 8-elem slots
    #pragma unroll
    for (int nt = 0; nt < 4; ++nt)
        #pragma unroll
        for (int r = 0; r < 4; ++r) {
            int row = fq * 4 + r;
            int col = gg * 64 + nt * 16 + fm;
            oB[row * 384 + (((col >> 3) ^ (row & 7)) << 3) + (col & 7)] = (__bf16)acco[nt][r];
        }
    __syncthreads();

    f32x4 acc2[4] = {};
    #pragma unroll
    for (int ks = 0; ks < 12; ++ks) {
        bf16x8 af = *(const bf16x8*)&oB[fm * 384 + (((ks * 4 + fq) ^ (fm & 7)) << 3)];
        #pragma unroll
        for (int nt = 0; nt < 4; ++nt) {
            bf16x8 bfr = *(const bf16x8*)&wot[(size_t)(gg * 64 + nt * 16 + fm) * 384 + ks * 32 + fq * 8];
            acc2[nt] = __builtin_amdgcn_mfma_f32_16x16x32_bf16(af, bfr, acc2[nt], 0, 0, 0);
        }
    }
    #pragma unroll
    for (int nt = 0; nt < 4; ++nt) {
        int col = gg * 64 + nt * 16 + fm;
        float bv = bo[col], lv = ls[col];
        #pragma unroll
        for (int r = 0; r < 4; ++r) {
            size_t idx = (size_t)(b * 256 + i0 + fq * 4 + r) * 384 + col;
            xf[idx] = (acc2[nt][r] + bv) * lv + xf[idx];
        }
    }
}

extern "C" void kernel_launch(void* const* d_in, const int* in_sizes, int n_in,
                              void* d_out, int out_size, void* d_ws, size_t ws_size,
                              hipStream_t stream) {
    const float* x      = (const float*)d_in[0];
    const float* ln1_g  = (const float*)d_in[1];
    const float* ln1_b  = (const float*)d_in[2];
    const float* wq     = (const float*)d_in[3];
    const float* wkv    = (const float*)d_in[4];
    const float* scale  = (const float*)d_in[5];
    const float* mixp   = (const float*)d_in[6];
    const float* mixq   = (const float*)d_in[7];
    const float* wo     = (const float*)d_in[8];
    const float* bo     = (const float*)d_in[9];
    const float* ls1    = (const float*)d_in[10];
    const float* ln2_g  = (const float*)d_in[11];
    const float* ln2_b  = (const float*)d_in[12];
    const float* w1     = (const float*)d_in[13];
    const float* b1     = (const float*)d_in[14];
    const float* w2     = (const float*)d_in[15];
    const float* b2     = (const float*)d_in[16];
    const float* ls2    = (const float*)d_in[17];

    char* ws = (char*)d_ws;
    float*  xf = (float*)ws;                      ws += (size_t)T_ * DIM_ * 4;
    __bf16* y  = (__bf16*)ws;                     ws += (size_t)T_ * DIM_ * 2;
    // q/kb/vT live inside a union region sized for the MLP hidden h [T][1536]
    // (25.2 MB > q+kb+vT = 18.9 MB). R7 BUG FIX: h previously overran into wbuf.
    __bf16* q  = (__bf16*)ws;
    __bf16* kb = q  + (size_t)T_ * DIM_;
    __bf16* vT = kb + (size_t)T_ * DIM_;
    __bf16* h  = q;                               // MLP hidden [T][1536], q/kb/vT dead by then
    ws += (size_t)T_ * MLP_ * 2;                  // reserve the FULL union extent
    __bf16* wbuf = (__bf16*)ws;                   ws += (size_t)WBUF_ELEMS * DEPTH_ * 2;

    size_t nBytes = (size_t)T_ * DIM_ * sizeof(float);
    hipMemcpyAsync(xf, x, nBytes, hipMemcpyDeviceToDevice, stream);

    // all-layer weight conversion up front (one dispatch)
    convert_w_all<<<432 * DEPTH_, 256, 0, stream>>>(wq, wkv, wo, w1, w2, wbuf);

    for (int l = 0; l < DEPTH_; ++l) {
        __bf16* wl = wbuf + (size_t)l * WBUF_ELEMS;

        ln1w<<<T_ / 4, 256, 0, stream>>>(xf, ln1_g + (size_t)l * DIM_, ln1_b + (size_t)l * DIM_, y);

        // QKV: 64 M-tiles x 9 N-tiles = 576 blocks
        gemmt<0, 384, 128, 128, 32, 9><<<576, 256, 0, stream>>>(
            y, wl + WQKV_OFF, nullptr, nullptr, nullptr, nullptr,
            q, kb, vT, 1152);

        // attention + fused O-proj/LayerScale/residual: 512 blocks, batch pinned to XCD
        attn_mfma<<<512, 384, 0, stream>>>(
            q, kb, vT, scale + (size_t)l * H_,
            mixp + (size_t)l * H_ * H_, mixq + (size_t)l * H_ * H_,
            wl + WO_OFF, bo + (size_t)l * DIM_, ls1 + (size_t)l * DIM_, xf);

        ln1w<<<T_ / 4, 256, 0, stream>>>(xf, ln2_g + (size_t)l * DIM_, ln2_b + (size_t)l * DIM_, y);

        // MLP1: 64 x 12 = 768 blocks
        gemmt<1, 384, 128, 128, 32, 12><<<768, 256, 0, stream>>>(
            y, wl + W1_OFF, b1 + (size_t)l * MLP_, nullptr,
            nullptr, h, nullptr, nullptr, nullptr, MLP_);

        // MLP2: 128 x 6 = 768 blocks (64x64, BK=64 swizzled, K=1536)
        gemmt<2, 1536, 64, 64, 64, 6><<<768, 256, 0, stream>>>(
            h, wl + W2_OFF, b2 + (size_t)l * DIM_, ls2 + (size_t)l * DIM_,
            xf, nullptr, nullptr, nullptr, nullptr, DIM_);
    }

    hipMemcpyAsync(d_out, xf, nBytes, hipMemcpyDeviceToDevice, stream);
}

// Round 9
// 1668.014 us; speedup vs baseline: 1.1304x; 1.0309x over previous
//
#include <hip/hip_runtime.h>
#include <hip/hip_bf16.h>
#include <math.h>

#define B_ 32
#define N_ 256
#define DIM_ 384
#define H_ 6
#define DH_ 64
#define INNER_ 384
#define MLP_ 1536
#define DEPTH_ 12
#define T_ (B_ * N_)   // 8192 tokens

typedef __bf16 bf16x8 __attribute__((ext_vector_type(8)));
typedef __bf16 bf16x4 __attribute__((ext_vector_type(4)));
typedef float f32x4 __attribute__((ext_vector_type(4)));

typedef const __attribute__((address_space(1))) void* gas_ptr;
typedef __attribute__((address_space(3))) void* las_ptr;

// wbuf layout (bf16, per layer, transposed [n][k])
#define WQKV_OFF 0                      // [1152][384]
#define WO_OFF   (1152 * 384)           // [384][384]
#define W1_OFF   (WO_OFF + 384 * 384)   // [1536][384]
#define W2_OFF   (W1_OFF + 1536 * 384)  // [384][1536]
#define WBUF_ELEMS (W2_OFF + 384 * 1536)

// ---------------- weight pre-pack, ALL layers in one dispatch ----------------
__global__ __launch_bounds__(256) void convert_w_all(
    const float* __restrict__ wq0, const float* __restrict__ wkv0,
    const float* __restrict__ wo0, const float* __restrict__ w10,
    const float* __restrict__ w20, __bf16* __restrict__ wbuf0)
{
    __shared__ float til[64][65];
    int t = blockIdx.x;
    int l = t / 432; t -= l * 432;
    const float* wq  = wq0  + (size_t)l * DIM_ * INNER_;
    const float* wkv = wkv0 + (size_t)l * DIM_ * 2 * INNER_;
    const float* wo  = wo0  + (size_t)l * INNER_ * DIM_;
    const float* w1  = w10  + (size_t)l * DIM_ * MLP_;
    const float* w2  = w20  + (size_t)l * MLP_ * DIM_;
    __bf16* wbuf = wbuf0 + (size_t)l * WBUF_ELEMS;

    int lane = threadIdx.x & 63, seg = threadIdx.x >> 6;
    const float* src; __bf16* dst;
    int Ns, sc, dK, dR, k0;
    if (t < 108) {                      // wqkv_t [1152][384]
        int nt = t / 6, kt = t % 6;
        int n0 = nt * 64; k0 = kt * 64;
        dst = wbuf + WQKV_OFF; dK = 384; dR = n0;
        if (n0 < 384) { src = wq;  Ns = 384; sc = n0; }
        else          { src = wkv; Ns = 768; sc = n0 - 384; }
    } else if (t < 144) {               // wo_t [384][384]
        int u = t - 108; int nt = u / 6, kt = u % 6;
        src = wo; Ns = 384; sc = nt * 64;
        dst = wbuf + WO_OFF; dK = 384; dR = nt * 64; k0 = kt * 64;
    } else if (t < 288) {               // w1_t [1536][384]
        int u = t - 144; int nt = u / 6, kt = u % 6;
        src = w1; Ns = 1536; sc = nt * 64;
        dst = wbuf + W1_OFF; dK = 384; dR = nt * 64; k0 = kt * 64;
    } else {                            // w2_t [384][1536]
        int u = t - 288; int nt = u / 24, kt = u % 24;
        src = w2; Ns = 384; sc = nt * 64;
        dst = wbuf + W2_OFF; dK = 1536; dR = nt * 64; k0 = kt * 64;
    }
    #pragma unroll
    for (int r = 0; r < 16; ++r) {
        int i = seg * 16 + r;
        til[i][lane] = src[(size_t)(k0 + i) * Ns + sc + lane];
    }
    __syncthreads();
    #pragma unroll
    for (int r = 0; r < 16; ++r) {
        int i = seg * 16 + r;
        dst[(size_t)(dR + i) * dK + k0 + lane] = (__bf16)til[lane][i];
    }
}

// ---------------- layernorm: wave per token, 4 tokens per block ----------
__global__ __launch_bounds__(256) void ln1w(
    const float* __restrict__ x, const float* __restrict__ g,
    const float* __restrict__ b, __bf16* __restrict__ y)
{
    size_t row = blockIdx.x * 4 + (threadIdx.x >> 6);
    int lane = threadIdx.x & 63;
    const float* xr = x + row * DIM_;
    float v[6];
    #pragma unroll
    for (int s = 0; s < 6; ++s) v[s] = xr[lane + 64 * s];
    float sum = 0.f;
    #pragma unroll
    for (int s = 0; s < 6; ++s) sum += v[s];
    #pragma unroll
    for (int o = 32; o > 0; o >>= 1) sum += __shfl_xor(sum, o);
    float mu = sum * (1.0f / DIM_);
    float var = 0.f;
    #pragma unroll
    for (int s = 0; s < 6; ++s) { float d = v[s] - mu; var += d * d; }
    #pragma unroll
    for (int o = 32; o > 0; o >>= 1) var += __shfl_xor(var, o);
    float rs = rsqrtf(var * (1.0f / DIM_) + 1e-5f);
    __bf16* yr = y + row * DIM_;
    #pragma unroll
    for (int s = 0; s < 6; ++s) {
        int e = lane + 64 * s;
        yr[e] = (__bf16)((v[s] - mu) * rs * g[e] + b[e]);
    }
}

// ---------------- m97-structure MFMA GEMM + counted-vmcnt pipeline (R4, verified) ----------
template<int MODE, int K, int BM, int BN, int BK, int NT>
__global__ __launch_bounds__(256) void gemmt(
    const __bf16* __restrict__ A, const __bf16* __restrict__ Bt,
    const float* __restrict__ bias, const float* __restrict__ ls,
    float* __restrict__ xf, __bf16* __restrict__ out,
    __bf16* __restrict__ oq, __bf16* __restrict__ ok, __bf16* __restrict__ ov,
    int Nn)
{
    constexpr int WM = BM / 32, WN = BN / 32;
    constexpr int KS = BK / 32;
    constexpr int MT = T_ / BM;
    constexpr int nIter = K / BK;
    constexpr bool SWZ = (BK == 64);
    constexpr int RPI = 512 / BK;                 // rows per stage instr (1 KB each)
    constexpr int CL  = BK / 8;                   // 16B col slots per row
    constexpr int LPT = BM / (4 * RPI) + BN / (4 * RPI);
    static_assert(LPT == 4, "vmcnt literals assume 4 loads per tile per wave");

    __shared__ __align__(16) __bf16 sA[2][BM * BK];
    __shared__ __align__(16) __bf16 sB[2][BN * BK];

    int id = blockIdx.x;
    constexpr int nxg = (MT * NT) / 8;
    int wg = (id & 7) * nxg + (id >> 3);          // bijective XCD-chunked swizzle
    int bm = (wg / NT) * BM;                      // bm SLOW within XCD chunk
    int bn = (wg % NT) * BN;                      // bn fast -> A-panel reuse in L2
    int tid = threadIdx.x;
    int lane = tid & 63, wid = tid >> 6;
    int wm = (wid & 1) * (BM / 2), wn = (wid >> 1) * (BN / 2);
    int fm = lane & 15, fq = lane >> 4;

    f32x4 acc[WM][WN] = {};

    int lr = lane / CL, lc = lane % CL;
    int lcs = SWZ ? (lc ^ lr) : lc;               // pre-swizzled source col slot
    const __bf16* aBase = A + (size_t)(bm + wid * RPI + lr) * K + lcs * 8;
    const __bf16* bBase = Bt + (size_t)(bn + wid * RPI + lr) * K + lcs * 8;

    auto stage = [&](int buf, int kk) {
        #pragma unroll
        for (int qI = 0; qI < BM / (4 * RPI); ++qI)
            __builtin_amdgcn_global_load_lds(
                (gas_ptr)(aBase + (size_t)(qI * 4 * RPI) * K + kk),
                (las_ptr)&sA[buf][qI * 2048 + wid * 512], 16, 0, 0);
        #pragma unroll
        for (int qI = 0; qI < BN / (4 * RPI); ++qI)
            __builtin_amdgcn_global_load_lds(
                (gas_ptr)(bBase + (size_t)(qI * 4 * RPI) * K + kk),
                (las_ptr)&sB[buf][qI * 2048 + wid * 512], 16, 0, 0);
    };

    stage(0, 0);   // 4 loads in flight

    #pragma unroll
    for (int i = 0; i < nIter; ++i) {
        int cur = i & 1;
        if (i + 1 < nIter) {
            stage(cur ^ 1, (i + 1) * BK);                      // +4 loads (next tile)
            asm volatile("s_waitcnt vmcnt(4)" ::: "memory");   // tile i resident
        } else {
            asm volatile("s_waitcnt vmcnt(0)" ::: "memory");
        }
        __builtin_amdgcn_s_barrier();
        __builtin_amdgcn_sched_barrier(0);

        bf16x8 af[KS][WM], bfr[KS][WN];
        #pragma unroll
        for (int ks = 0; ks < KS; ++ks) {
            #pragma unroll
            for (int ii = 0; ii < WM; ++ii) {
                int row = wm + ii * 16 + fm;
                int c = SWZ ? (((ks * 4 + fq) ^ (row & 7)) * 8) : (ks * 32 + fq * 8);
                af[ks][ii] = *(const bf16x8*)&sA[cur][row * BK + c];
            }
            #pragma unroll
            for (int jj = 0; jj < WN; ++jj) {
                int row = wn + jj * 16 + fm;
                int c = SWZ ? (((ks * 4 + fq) ^ (row & 7)) * 8) : (ks * 32 + fq * 8);
                bfr[ks][jj] = *(const bf16x8*)&sB[cur][row * BK + c];
            }
        }
        #pragma unroll
        for (int ks = 0; ks < KS; ++ks)
            #pragma unroll
            for (int ii = 0; ii < WM; ++ii)
                #pragma unroll
                for (int jj = 0; jj < WN; ++jj)
                    acc[ii][jj] = __builtin_amdgcn_mfma_f32_16x16x32_bf16(
                        af[ks][ii], bfr[ks][jj], acc[ii][jj], 0, 0, 0);

        if (i + 1 < nIter) {
            asm volatile("s_waitcnt lgkmcnt(0)" ::: "memory");
            __builtin_amdgcn_sched_barrier(0);
            __builtin_amdgcn_s_barrier();
            __builtin_amdgcn_sched_barrier(0);
        }
    }

    // epilogue: C/D layout col=lane&15, row=(lane>>4)*4+reg
    #pragma unroll
    for (int jj = 0; jj < WN; ++jj) {
        int col = bn + wn + jj * 16 + fm;
        float bv = (MODE != 0) ? bias[col] : 0.0f;
        float lv = (MODE == 2) ? ls[col] : 0.0f;
        #pragma unroll
        for (int ii = 0; ii < WM; ++ii) {
            #pragma unroll
            for (int r = 0; r < 4; ++r) {
                int row = bm + wm + ii * 16 + fq * 4 + r;
                float v = acc[ii][jj][r];
                if (MODE == 0) {
                    if (col < 384)      oq[(size_t)row * 384 + col] = (__bf16)v;
                    else if (col < 768) ok[(size_t)row * 384 + col - 384] = (__bf16)v;
                    else {
                        int bb = row >> 8, tj = row & 255;
                        ov[((size_t)bb * 384 + (col - 768)) * 256 + tj] = (__bf16)v;
                    }
                } else if (MODE == 1) {
                    v += bv;
                    v = 0.5f * v * (1.0f + erff(v * 0.70710678118f));
                    out[(size_t)row * Nn + col] = (__bf16)v;
                } else {
                    size_t idx = (size_t)row * Nn + col;
                    xf[idx] = (v + bv) * lv + xf[idx];
                }
            }
        }
    }
}

// ---------------- fused MFMA talking-heads attention (v3 + T5 setprio) ----------------
// Phases: QK^T -> fused premix/mask/softmax/postmix (in-register) -> PV. 2 barriers.
// s_setprio(1) around MFMA clusters (T5): independent blocks per CU sit at different
// phases, so the CU scheduler can favor MFMA-issuing waves (+4-7% measured on attn).
#define PAD_S 264

__global__ __launch_bounds__(384) void attn_mfma(
    const __bf16* __restrict__ q, const __bf16* __restrict__ kb,
    const __bf16* __restrict__ vT, const float* __restrict__ scale,
    const float* __restrict__ mp, const float* __restrict__ mq,
    __bf16* __restrict__ o)
{
    __shared__ __bf16 sbuf[96][PAD_S];

    int id = blockIdx.x;
    int b = (id & 7) + ((id >> 3) & 3) * 8;
    int i0 = (id >> 5) * 16;
    int tid = threadIdx.x;
    int lane = tid & 63, wid = tid >> 6;
    int fm = lane & 15, fq = lane >> 4;

    // ---- Phase 1 — QK^T: wave h computes raw S_h[16][256] ----
    int h = wid;
    bf16x8 qf[2];
    #pragma unroll
    for (int ks = 0; ks < 2; ++ks)
        qf[ks] = *(const bf16x8*)&q[(size_t)(b * 256 + i0 + fm) * 384 + h * 64 + ks * 32 + fq * 8];
    #pragma unroll 4
    for (int jt = 0; jt < 16; ++jt) {
        f32x4 a = {};
        bf16x8 bf0 = *(const bf16x8*)&kb[(size_t)(b * 256 + jt * 16 + fm) * 384 + h * 64 + fq * 8];
        bf16x8 bf1 = *(const bf16x8*)&kb[(size_t)(b * 256 + jt * 16 + fm) * 384 + h * 64 + 32 + fq * 8];
        __builtin_amdgcn_s_setprio(1);
        a = __builtin_amdgcn_mfma_f32_16x16x32_bf16(qf[0], bf0, a, 0, 0, 0);
        a = __builtin_amdgcn_mfma_f32_16x16x32_bf16(qf[1], bf1, a, 0, 0, 0);
        __builtin_amdgcn_s_setprio(0);
        #pragma unroll
        for (int r = 0; r < 4; ++r)
            sbuf[h * 16 + fq * 4 + r][jt * 16 + fm] = (__bf16)a[r];
    }

    float mps[36], mqs[36];
    #pragma unroll
    for (int t = 0; t < 36; ++t) { mps[t] = mp[t] * scale[t / 6]; mqs[t] = mq[t]; }

    __syncthreads();

    // ---- Phase 2 — fused premix + mask + softmax + postmix, wave per row ----
    for (int i = wid; i < 16; i += 6) {
        float sv[6][4];
        #pragma unroll
        for (int h2 = 0; h2 < 6; ++h2) {
            bf16x4 v4 = *(const bf16x4*)&sbuf[h2 * 16 + i][lane * 4];
            #pragma unroll
            for (int c = 0; c < 4; ++c) sv[h2][c] = (float)v4[c];
        }
        int drow = i0 + i;
        float pv[6][4];
        #pragma unroll
        for (int g2 = 0; g2 < 6; ++g2) {
            float t0[4];
            #pragma unroll
            for (int c = 0; c < 4; ++c) {
                float r2 = 0.f;
                #pragma unroll
                for (int h2 = 0; h2 < 6; ++h2) r2 += sv[h2][c] * mps[h2 * 6 + g2];
                t0[c] = (lane * 4 + c == drow) ? -1e30f : r2;
            }
            float m = fmaxf(fmaxf(t0[0], t0[1]), fmaxf(t0[2], t0[3]));
            #pragma unroll
            for (int off = 32; off > 0; off >>= 1) m = fmaxf(m, __shfl_xor(m, off));
            float e0 = __expf(t0[0] - m), e1 = __expf(t0[1] - m);
            float e2 = __expf(t0[2] - m), e3 = __expf(t0[3] - m);
            float s = e0 + e1 + e2 + e3;
            #pragma unroll
            for (int off = 32; off > 0; off >>= 1) s += __shfl_xor(s, off);
            float inv = 1.0f / s;
            pv[g2][0] = e0 * inv; pv[g2][1] = e1 * inv;
            pv[g2][2] = e2 * inv; pv[g2][3] = e3 * inv;
        }
        #pragma unroll
        for (int g2 = 0; g2 < 6; ++g2) {
            bf16x4 w4;
            #pragma unroll
            for (int c = 0; c < 4; ++c) {
                float r2 = 0.f;
                #pragma unroll
                for (int h2 = 0; h2 < 6; ++h2) r2 += pv[h2][c] * mqs[h2 * 6 + g2];
                w4[c] = (__bf16)r2;
            }
            *(bf16x4*)&sbuf[g2 * 16 + i][lane * 4] = w4;
        }
    }
    __syncthreads();

    // ---- Phase 3 — P @ V ----
    int gg = wid;
    f32x4 acco[4] = {};
    #pragma unroll
    for (int jc = 0; jc < 4; ++jc) {
        #pragma unroll
        for (int ks = 0; ks < 2; ++ks) {
            bf16x8 af = *(const bf16x8*)&sbuf[gg * 16 + fm][jc * 64 + ks * 32 + fq * 8];
            bf16x8 bfr[4];
            #pragma unroll
            for (int nt = 0; nt < 4; ++nt)
                bfr[nt] = *(const bf16x8*)&vT[(size_t)(b * 384 + gg * 64 + nt * 16 + fm) * 256 + jc * 64 + ks * 32 + fq * 8];
            __builtin_amdgcn_s_setprio(1);
            #pragma unroll
            for (int nt = 0; nt < 4; ++nt)
                acco[nt] = __builtin_amdgcn_mfma_f32_16x16x32_bf16(af, bfr[nt], acco[nt], 0, 0, 0);
            __builtin_amdgcn_s_setprio(0);
        }
    }
    #pragma unroll
    for (int nt = 0; nt < 4; ++nt)
        #pragma unroll
        for (int r = 0; r < 4; ++r)
            o[(size_t)(b * 256 + i0 + fq * 4 + r) * 384 + gg * 64 + nt * 16 + fm] = (__bf16)acco[nt][r];
}

extern "C" void kernel_launch(void* const* d_in, const int* in_sizes, int n_in,
                              void* d_out, int out_size, void* d_ws, size_t ws_size,
                              hipStream_t stream) {
    const float* x      = (const float*)d_in[0];
    const float* ln1_g  = (const float*)d_in[1];
    const float* ln1_b  = (const float*)d_in[2];
    const float* wq     = (const float*)d_in[3];
    const float* wkv    = (const float*)d_in[4];
    const float* scale  = (const float*)d_in[5];
    const float* mixp   = (const float*)d_in[6];
    const float* mixq   = (const float*)d_in[7];
    const float* wo     = (const float*)d_in[8];
    const float* bo     = (const float*)d_in[9];
    const float* ls1    = (const float*)d_in[10];
    const float* ln2_g  = (const float*)d_in[11];
    const float* ln2_b  = (const float*)d_in[12];
    const float* w1     = (const float*)d_in[13];
    const float* b1     = (const float*)d_in[14];
    const float* w2     = (const float*)d_in[15];
    const float* b2     = (const float*)d_in[16];
    const float* ls2    = (const float*)d_in[17];

    char* ws = (char*)d_ws;
    float*  xf = (float*)ws;                      ws += (size_t)T_ * DIM_ * 4;
    __bf16* y  = (__bf16*)ws;                     ws += (size_t)T_ * DIM_ * 2;
    __bf16* q  = (__bf16*)ws;                     ws += (size_t)T_ * DIM_ * 2;
    __bf16* kb = (__bf16*)ws;                     ws += (size_t)T_ * DIM_ * 2;
    __bf16* vT = (__bf16*)ws;                     ws += (size_t)T_ * DIM_ * 2;
    __bf16* o  = (__bf16*)ws;                     ws += (size_t)T_ * DIM_ * 2;
    __bf16* wbuf = (__bf16*)ws;                   ws += (size_t)WBUF_ELEMS * DEPTH_ * 2;
    __bf16* h  = q;   // MLP hidden [T][1536] overlays q+kb+vT+o (25.2MB, exact fit)

    size_t nBytes = (size_t)T_ * DIM_ * sizeof(float);
    hipMemcpyAsync(xf, x, nBytes, hipMemcpyDeviceToDevice, stream);

    // all-layer weight conversion up front (one dispatch)
    convert_w_all<<<432 * DEPTH_, 256, 0, stream>>>(wq, wkv, wo, w1, w2, wbuf);

    for (int l = 0; l < DEPTH_; ++l) {
        __bf16* wl = wbuf + (size_t)l * WBUF_ELEMS;

        ln1w<<<T_ / 4, 256, 0, stream>>>(xf, ln1_g + (size_t)l * DIM_, ln1_b + (size_t)l * DIM_, y);

        // QKV: 64 M-tiles x 9 N-tiles = 576 blocks
        gemmt<0, 384, 128, 128, 32, 9><<<576, 256, 0, stream>>>(
            y, wl + WQKV_OFF, nullptr, nullptr, nullptr, nullptr,
            q, kb, vT, 1152);

        // attention: 512 blocks, batch pinned to XCD
        attn_mfma<<<512, 384, 0, stream>>>(
            q, kb, vT, scale + (size_t)l * H_,
            mixp + (size_t)l * H_ * H_, mixq + (size_t)l * H_ * H_, o);

        // O-proj: 128 x 6 = 768 blocks (64x64, BK=64 swizzled)
        gemmt<2, 384, 64, 64, 64, 6><<<768, 256, 0, stream>>>(
            o, wl + WO_OFF, bo + (size_t)l * DIM_, ls1 + (size_t)l * DIM_,
            xf, nullptr, nullptr, nullptr, nullptr, DIM_);

        ln1w<<<T_ / 4, 256, 0, stream>>>(xf, ln2_g + (size_t)l * DIM_, ln2_b + (size_t)l * DIM_, y);

        // MLP1: 64 x 12 = 768 blocks
        gemmt<1, 384, 128, 128, 32, 12><<<768, 256, 0, stream>>>(
            y, wl + W1_OFF, b1 + (size_t)l * MLP_, nullptr,
            nullptr, h, nullptr, nullptr, nullptr, MLP_);

        // MLP2: 128 x 6 = 768 blocks (64x64, BK=64 swizzled, K=1536)
        gemmt<2, 1536, 64, 64, 64, 6><<<768, 256, 0, stream>>>(
            h, wl + W2_OFF, b2 + (size_t)l * DIM_, ls2 + (size_t)l * DIM_,
            xf, nullptr, nullptr, nullptr, nullptr, DIM_);
    }

    hipMemcpyAsync(d_out, xf, nBytes, hipMemcpyDeviceToDevice, stream);
}